// Round 7
// baseline (338.479 us; speedup 1.0000x reference)
//
#include <hip/hip_runtime.h>
#include <stdint.h>

#define K_DIM 1024
#define N_DIM 1024
#define M_DIM 65536

typedef __bf16 bf16_t;
typedef __bf16 bf16x8 __attribute__((ext_vector_type(8)));
typedef float f32x4 __attribute__((ext_vector_type(4)));

#define GLOAD_LDS16(g, l) __builtin_amdgcn_global_load_lds( \
    (const __attribute__((address_space(1))) void*)(g),     \
    (__attribute__((address_space(3))) void*)(l), 16, 0, 0)

#define VMCNT(n) asm volatile("s_waitcnt vmcnt(%0)" ::"n"(n) : "memory")
#define LGKM(n) asm volatile("s_waitcnt lgkmcnt(%0)" ::"n"(n) : "memory")
#define SCHEDB() __builtin_amdgcn_sched_barrier(0)

// ---------------------------------------------------------------------------
// Quantize-dequantize to bf16 (unchanged semantics; blocks [0,512) do w,
// the rest grid-stride x).
// ---------------------------------------------------------------------------
__global__ __launch_bounds__(256) void quant_dequant_kernel(
    const float* __restrict__ x, bf16_t* __restrict__ xd, long long nx,
    const float* __restrict__ w, bf16_t* __restrict__ wd, long long nw) {
  const float* in;
  bf16_t* out;
  long long i, stride, n;
  if (blockIdx.x < 512) {
    in = w; out = wd; n = nw;
    i = (long long)blockIdx.x * blockDim.x + threadIdx.x;
    stride = 512ll * blockDim.x;
  } else {
    in = x; out = xd; n = nx;
    i = (long long)(blockIdx.x - 512) * blockDim.x + threadIdx.x;
    stride = (long long)(gridDim.x - 512) * blockDim.x;
  }
  for (; i < n; i += stride) {
    long long base = i * 8;
    f32x4 v0 = *reinterpret_cast<const f32x4*>(in + base);
    f32x4 v1 = *reinterpret_cast<const f32x4*>(in + base + 4);
    float mx = 0.0f;
#pragma unroll
    for (int j = 0; j < 4; ++j) {
      mx = fmaxf(mx, fabsf(v0[j]));
      mx = fmaxf(mx, fabsf(v1[j]));
    }
    mx = fmaxf(mx, __shfl_xor(mx, 1));
    mx = fmaxf(mx, __shfl_xor(mx, 2));
    float s = fmaxf(mx / 7.5f, 1e-30f);
    bf16x8 o;
#pragma unroll
    for (int j = 0; j < 8; ++j) {
      float xv = (j < 4) ? v0[j] : v1[j - 4];
      float y = xv / s;  // fp32 div, like reference
      float m = fabsf(y);
      float h, hinv;
      if (m < 2.0f)      { h = 0.125f; hinv = 8.0f; }
      else if (m < 4.0f) { h = 0.25f;  hinv = 4.0f; }
      else               { h = 0.5f;   hinv = 2.0f; }
      float nn = m * hinv;  // exact (power-of-2 scale)
      float kf = floorf(nn);
      float fr = nn - kf;   // exact
      float up = (fr > 0.5f || (fr == 0.5f && y < 0.0f)) ? 1.0f : 0.0f;
      float q = fminf((kf + up) * h, 7.5f);
      o[j] = (bf16_t)(copysignf(q, y) * s);
    }
    *reinterpret_cast<bf16x8*>(out + base) = o;
  }
}

// ---------------------------------------------------------------------------
// bf16 GEMM C = A*B^T + bias.  Round-7 restructure: cross-BLOCK overlap.
//  * Block = 256 threads (4 waves, 2m x 2n), tile 256x128, per-wave 128x64.
//  * B (2MB, L2-resident) -> registers, double-buffered, prefetched 1 slice
//    ahead under counted vmcnt (never 0 in steady state).
//  * A staged via global_load_lds into 4-deep ring of A[256][32] chunks
//    (64 KB LDS) -> TWO blocks resident per CU: independent blocks provide
//    the pipe overlap that barrier-locked waves of one block cannot.
//  * One barrier + two counted vmcnts per slice:
//      top:    vmcnt(8)  retires A(s)   (staged 2 slices ago, HBM covered)
//      preMFMA:vmcnt(12) retires B(s)   (issued 1 slice ago, L2 covered)
//    Queue invariant at slice top: [A(s)4, B(s)4, A(s+1)4] = 12.
//  * Zero-conflict LDS swizzle family (r3/r6-verified, 0 conflicts).
// Safety: top-barrier(s) implies every wave finished slice s-1 (incl. its
// lgkm(0)-retired reads of ring slot (s-2)&3) before any wave issues
// STAGE(s+2) into that slot; reads of A(s) follow all waves' vmcnt(8).
// ---------------------------------------------------------------------------
__global__ __launch_bounds__(256, 2) void mx_gemm(
    const bf16_t* __restrict__ A, const bf16_t* __restrict__ B,
    const float* __restrict__ bias, float* __restrict__ C) {
  __shared__ char lds[65536];  // 4 x A[256][32] bf16 chunks

  const int tid = threadIdx.x;
  const int lane = tid & 63;
  const int wid = tid >> 6;
  const int wm = wid >> 1;  // 0..1 (128-row half)
  const int wn = wid & 1;   // 0..1 (64-col slice)

  // XCD-grouped mapping: 2048 blocks; 8 n-tiles of one m-panel stay on one
  // XCD (A panel fetched once into that XCD's L2; B 2MB L2-resident).
  const int b = blockIdx.x;
  const int xcd = b & 7;
  const int t = b >> 3;
  const int m_tile = xcd * 32 + (t >> 3);  // [0,256)
  const int n_tile = t & 7;                // [0,8)

  // A staging source (pre-swizzled): dest byte = g*4096 + tid*16 ->
  // row = g*64 + (tid>>2), phys slot = tid&3, logical col8 = (tid&3)^((tid>>3)&3).
  const int R0 = tid >> 2;
  const int c0 = ((tid & 3) ^ ((tid >> 3) & 3)) * 8;
  const bf16_t* aSg[4];
#pragma unroll
  for (int g = 0; g < 4; ++g)
    aSg[g] = A + (size_t)(m_tile * 256 + g * 64 + R0) * K_DIM + c0;
  const int dst16 = tid * 16;

  // A fragment ds_read offsets (zero-conflict family, lane-only swizzle).
  const int swz = (((lane >> 4) ^ ((lane >> 1) & 3)) << 4);
  const int aRd = (wm * 128 + (lane & 15)) * 64 + swz;  // + i*1024, i=0..7

  // B-frag global byte offsets: frag j: row = n_tile*128 + wn*64 + j*16 +
  // (lane&15); elems k0 + (lane>>4)*8.
  const char* Bb = (const char*)B;
  int boff[4];
#pragma unroll
  for (int j = 0; j < 4; ++j)
    boff[j] = (n_tile * 128 + wn * 64 + j * 16 + (lane & 15)) * 2048 +
              (lane >> 4) * 16;

  f32x4 acc[8][4];
#pragma unroll
  for (int i = 0; i < 8; ++i)
#pragma unroll
    for (int j = 0; j < 4; ++j) acc[i][j] = (f32x4)(0.0f);

  bf16x8 bfr[2][4];

#define SLICE(Q, VTOP, VB, DO_B, DO_STG)                                     \
  {                                                                          \
    VMCNT(VTOP);                                                             \
    __builtin_amdgcn_s_barrier();                                            \
    SCHEDB();                                                                \
    const char* sb_ = lds + ((Q) & 3) * 16384;                               \
    bf16x8 af[8];                                                            \
    _Pragma("unroll") for (int i = 0; i < 8; ++i) af[i] =                    \
        *reinterpret_cast<const bf16x8*>(sb_ + aRd + i * 1024);              \
    if (DO_B) {                                                              \
      _Pragma("unroll") for (int j = 0; j < 4; ++j)                          \
          bfr[((Q) + 1) & 1][j] = *reinterpret_cast<const bf16x8*>(          \
              Bb + boff[j] + ((Q) + 1) * 64);                                \
    }                                                                        \
    if (DO_STG) {                                                            \
      _Pragma("unroll") for (int g = 0; g < 4; ++g)                          \
          GLOAD_LDS16(aSg[g] + ((Q) + 2) * 32,                               \
                      lds + (((Q) + 2) & 3) * 16384 + g * 4096 + dst16);     \
    }                                                                        \
    SCHEDB();                                                                \
    VMCNT(VB);                                                               \
    LGKM(0);                                                                 \
    SCHEDB();                                                                \
    __builtin_amdgcn_s_setprio(1);                                           \
    _Pragma("unroll") for (int i = 0; i < 8; ++i)                            \
        _Pragma("unroll") for (int j = 0; j < 4; ++j) acc[i][j] =            \
            __builtin_amdgcn_mfma_f32_16x16x32_bf16(af[i], bfr[(Q) & 1][j],  \
                                                    acc[i][j], 0, 0, 0);     \
    __builtin_amdgcn_s_setprio(0);                                           \
  }

  // Prologue: A(0) | B(0) | A(1)  -> queue [A0(4), B0(4), A1(4)] = 12.
#pragma unroll
  for (int g = 0; g < 4; ++g)
    GLOAD_LDS16(aSg[g], lds + g * 4096 + dst16);
#pragma unroll
  for (int j = 0; j < 4; ++j)
    bfr[0][j] = *reinterpret_cast<const bf16x8*>(Bb + boff[j]);
#pragma unroll
  for (int g = 0; g < 4; ++g)
    GLOAD_LDS16(aSg[g] + 32, lds + 16384 + g * 4096 + dst16);

  // Slices 0..27 in 7 groups of 4 (ring period); pointer advance keeps all
  // LDS offsets compile-time immediates.
  for (int grp = 0; grp < 7; ++grp) {
    SLICE(0, 8, 12, 1, 1);
    SLICE(1, 8, 12, 1, 1);
    SLICE(2, 8, 12, 1, 1);
    SLICE(3, 8, 12, 1, 1);
#pragma unroll
    for (int g = 0; g < 4; ++g) aSg[g] += 128;  // 4 slices * 32 elems
#pragma unroll
    for (int j = 0; j < 4; ++j) boff[j] += 256;
  }
  // s=28 (stages A(30)), s=29 (stages A(31)).
  SLICE(0, 8, 12, 1, 1);
  SLICE(1, 8, 12, 1, 1);
  // s=30: no stage; after issuing B(31): [B30,A31,B31]=12 -> retire B30: 8.
  SLICE(2, 8, 8, 1, 0);
  // s=31: top [A31,B31]=8 -> retire A31: vmcnt(4); then retire B31: vmcnt(0).
  SLICE(3, 4, 0, 0, 0);

  // Epilogue. C/D layout: col = lane&15, row = (lane>>4)*4 + reg (m89).
  const int col0 = n_tile * 128 + wn * 64 + (lane & 15);
  const int row0 = m_tile * 256 + wm * 128 + ((lane >> 4) << 2);
#pragma unroll
  for (int j = 0; j < 4; ++j) {
    float bv = bias[col0 + j * 16];
#pragma unroll
    for (int m = 0; m < 8; ++m) {
#pragma unroll
      for (int r = 0; r < 4; ++r) {
        C[(size_t)(row0 + m * 16 + r) * N_DIM + col0 + j * 16] =
            acc[m][j][r] + bv;
      }
    }
  }
#undef SLICE
}

extern "C" void kernel_launch(void* const* d_in, const int* in_sizes, int n_in,
                              void* d_out, int out_size, void* d_ws,
                              size_t ws_size, hipStream_t stream) {
  const float* x = (const float*)d_in[0];     // 8*8192*1024 fp32
  const float* w = (const float*)d_in[1];     // 1024*1024 fp32
  const float* bias = (const float*)d_in[2];  // 1024 fp32
  float* out = (float*)d_out;                 // 65536*1024 fp32

  bf16_t* xd = (bf16_t*)d_ws;               // 128 MB
  bf16_t* wd = xd + (size_t)M_DIM * K_DIM;  // +2 MB

  quant_dequant_kernel<<<4608, 256, 0, stream>>>(
      x, xd, (long long)M_DIM * K_DIM / 8, w, wd,
      (long long)K_DIM * N_DIM / 8);

  mx_gemm<<<(M_DIM / 256) * (N_DIM / 128), 256, 0, stream>>>(xd, wd, bias,
                                                             out);
}

// Round 8
// 275.214 us; speedup vs baseline: 1.2299x; 1.2299x over previous
//
#include <hip/hip_runtime.h>
#include <stdint.h>

#define K_DIM 1024
#define N_DIM 1024
#define M_DIM 65536

typedef __bf16 bf16_t;
typedef __bf16 bf16x8 __attribute__((ext_vector_type(8)));
typedef float f32x4 __attribute__((ext_vector_type(4)));

#define GLOAD_LDS16(g, l) __builtin_amdgcn_global_load_lds( \
    (const __attribute__((address_space(1))) void*)(g),     \
    (__attribute__((address_space(3))) void*)(l), 16, 0, 0)

#define VMCNT(n) asm volatile("s_waitcnt vmcnt(%0)" ::"n"(n) : "memory")
#define LGKM(n) asm volatile("s_waitcnt lgkmcnt(%0)" ::"n"(n) : "memory")

// ---------------------------------------------------------------------------
// Quantize-dequantize to bf16 (unchanged semantics; blocks [0,512) do w,
// the rest grid-stride x).
// ---------------------------------------------------------------------------
__global__ __launch_bounds__(256) void quant_dequant_kernel(
    const float* __restrict__ x, bf16_t* __restrict__ xd, long long nx,
    const float* __restrict__ w, bf16_t* __restrict__ wd, long long nw) {
  const float* in;
  bf16_t* out;
  long long i, stride, n;
  if (blockIdx.x < 512) {
    in = w; out = wd; n = nw;
    i = (long long)blockIdx.x * blockDim.x + threadIdx.x;
    stride = 512ll * blockDim.x;
  } else {
    in = x; out = xd; n = nx;
    i = (long long)(blockIdx.x - 512) * blockDim.x + threadIdx.x;
    stride = (long long)(gridDim.x - 512) * blockDim.x;
  }
  for (; i < n; i += stride) {
    long long base = i * 8;
    f32x4 v0 = *reinterpret_cast<const f32x4*>(in + base);
    f32x4 v1 = *reinterpret_cast<const f32x4*>(in + base + 4);
    float mx = 0.0f;
#pragma unroll
    for (int j = 0; j < 4; ++j) {
      mx = fmaxf(mx, fabsf(v0[j]));
      mx = fmaxf(mx, fabsf(v1[j]));
    }
    mx = fmaxf(mx, __shfl_xor(mx, 1));
    mx = fmaxf(mx, __shfl_xor(mx, 2));
    float s = fmaxf(mx / 7.5f, 1e-30f);
    bf16x8 o;
#pragma unroll
    for (int j = 0; j < 8; ++j) {
      float xv = (j < 4) ? v0[j] : v1[j - 4];
      float y = xv / s;  // fp32 div, like reference
      float m = fabsf(y);
      float h, hinv;
      if (m < 2.0f)      { h = 0.125f; hinv = 8.0f; }
      else if (m < 4.0f) { h = 0.25f;  hinv = 4.0f; }
      else               { h = 0.5f;   hinv = 2.0f; }
      float nn = m * hinv;  // exact (power-of-2 scale)
      float kf = floorf(nn);
      float fr = nn - kf;   // exact
      float up = (fr > 0.5f || (fr == 0.5f && y < 0.0f)) ? 1.0f : 0.0f;
      float q = fminf((kf + up) * h, 7.5f);
      o[j] = (bf16_t)(copysignf(q, y) * s);
    }
    *reinterpret_cast<bf16x8*>(out + base) = o;
  }
}

// ---------------------------------------------------------------------------
// bf16 GEMM C = A*B^T + bias — r6 structure with the scheduling fences
// REMOVED (r8 A/B experiment: over-fencing theory).
// 256x256 tile, 512 threads = 8 waves (2M x 4N), K as 32 slices of 32.
// LDS = ring of 8 chunks of 16 KB (128 KB): slot(A(s))=(2s)&7, slot(B(s))=
// (2s+1)&7. Slice s = 2 phases (16 MFMA each); P0 stages {A,B}(s+2);
// P1 has the single counted VMCNT(4) (retires {A,B}(s+1); queue never
// drains in steady state). NO sched_barrier / NO asm lgkmcnt around the
// read->MFMA path: the compiler inserts fine-grained per-MFMA lgkmcnt(N)
// (m97 evidence), letting early-served waves MFMA while the LDS FIFO still
// serves others. setprio(1) pins the MFMA cluster between barriers (side-
// effecting intrinsics keep program order among themselves).
// Safety (unchanged from r6, HW-barrier based, compiler-independent):
//  * reads of slice s follow every wave's VMCNT at P1(s-1) + barrier;
//  * ds_reads of slot v are consumed by MFMAs (compiler lgkmcnt) before the
//    wave reaches the following barrier, and the stage overwriting slot v
//    is issued 2 slices (4+ barriers) later;
//  * a wave's own stages are retired by its own counted VMCNT one slice
//    before any wave reads that slot (barrier-ordered).
// Swizzle: phys 16B slot = logical ^ ((row>>1)&3) — 0 conflicts (r3/r4/r6
// measured); staging source inverse-pre-swizzled (both-sides-or-neither).
// ---------------------------------------------------------------------------
__global__ __launch_bounds__(512, 2) void mx_gemm(
    const bf16_t* __restrict__ A, const bf16_t* __restrict__ B,
    const float* __restrict__ bias, float* __restrict__ C) {
  __shared__ char lds[131072];

  const int tid = threadIdx.x;
  const int lane = tid & 63;
  const int wid = tid >> 6;
  const int wm = wid >> 2;  // 0..1  (128-row half)
  const int wn = wid & 3;   // 0..3  (64-col slice)

  // XCD-grouped mapping (verified: A ~once from HBM; B L2-resident).
  const int b = blockIdx.x;
  const int xcd = b & 7;
  const int t = b >> 3;
  const int m_tile = xcd * 32 + (t >> 2);  // [0,256)
  const int n_tile = t & 3;                // [0,4)

  // Staging source (pre-swizzled): dest row R = tid>>2 (load0) / +128
  // (load1); source col8 = (tid&3) ^ ((tid>>3)&3).
  const int R0 = tid >> 2;
  const int c0 = ((tid & 3) ^ ((tid >> 3) & 3)) * 8;
  const bf16_t* aS0 = A + (size_t)(m_tile * 256 + R0) * K_DIM + c0;
  const bf16_t* aS1 = aS0 + (size_t)128 * K_DIM;
  const bf16_t* bS0 = B + (size_t)(n_tile * 256 + R0) * K_DIM + c0;
  const bf16_t* bS1 = bS0 + (size_t)128 * K_DIM;
  const int dst16 = tid * 16;

#define STG_A(KOFF, SLOT)                           \
  {                                                 \
    char* d_ = lds + (SLOT) * 16384 + dst16;        \
    GLOAD_LDS16(aS0 + (KOFF), d_);                  \
    GLOAD_LDS16(aS1 + (KOFF), d_ + 8192);           \
  }
#define STG_B(KOFF, SLOT)                           \
  {                                                 \
    char* d_ = lds + (SLOT) * 16384 + dst16;        \
    GLOAD_LDS16(bS0 + (KOFF), d_);                  \
    GLOAD_LDS16(bS1 + (KOFF), d_ + 8192);           \
  }

  // Fragment ds_read offsets (zero-conflict family, lane-only swizzle).
  const int swz = (((lane >> 4) ^ ((lane >> 1) & 3)) << 4);
  const int aRd = (wm * 128 + (lane & 15)) * 64 + swz;  // + i*1024, i=0..7
  const int bRd = (wn * 64 + (lane & 15)) * 64 + swz;   // + j*1024, j=0..3

  f32x4 acc[8][4];
#pragma unroll
  for (int i = 0; i < 8; ++i)
#pragma unroll
    for (int j = 0; j < 4; ++j) acc[i][j] = (f32x4)(0.0f);

#define SLICE(SQ, KOFF, DO_STG, DO_V, VN)                                    \
  {                                                                          \
    const char* cA_ = lds + (((2 * (SQ)) & 7) * 16384);                      \
    const char* cB_ = lds + (((2 * (SQ) + 1) & 7) * 16384);                  \
    bf16x8 af[4], bf[4];                                                     \
    /* ---- P0 ---- */                                                       \
    _Pragma("unroll") for (int i = 0; i < 4; ++i) af[i] =                    \
        *reinterpret_cast<const bf16x8*>(cA_ + aRd + i * 1024);              \
    _Pragma("unroll") for (int j = 0; j < 4; ++j) bf[j] =                    \
        *reinterpret_cast<const bf16x8*>(cB_ + bRd + j * 1024);              \
    if (DO_STG) {                                                            \
      STG_A((KOFF) + 64, ((2 * (SQ) + 4) & 7));                              \
      STG_B((KOFF) + 64, ((2 * (SQ) + 5) & 7));                              \
    }                                                                        \
    __builtin_amdgcn_s_barrier();                                            \
    __builtin_amdgcn_s_setprio(1);                                           \
    _Pragma("unroll") for (int i = 0; i < 4; ++i)                            \
        _Pragma("unroll") for (int j = 0; j < 4; ++j) acc[i][j] =            \
            __builtin_amdgcn_mfma_f32_16x16x32_bf16(af[i], bf[j],            \
                                                    acc[i][j], 0, 0, 0);     \
    __builtin_amdgcn_s_setprio(0);                                           \
    __builtin_amdgcn_s_barrier();                                            \
    /* ---- P1 ---- */                                                       \
    _Pragma("unroll") for (int i = 0; i < 4; ++i) af[i] =                    \
        *reinterpret_cast<const bf16x8*>(cA_ + aRd + 4096 + i * 1024);       \
    if (DO_V) { VMCNT(VN); }                                                 \
    __builtin_amdgcn_s_barrier();                                            \
    __builtin_amdgcn_s_setprio(1);                                           \
    _Pragma("unroll") for (int i = 0; i < 4; ++i)                            \
        _Pragma("unroll") for (int j = 0; j < 4; ++j) acc[4 + i][j] =        \
            __builtin_amdgcn_mfma_f32_16x16x32_bf16(af[i], bf[j],            \
                                                    acc[4 + i][j], 0, 0, 0); \
    __builtin_amdgcn_s_setprio(0);                                           \
    LGKM(0); /* free (reads consumed); fences ring reuse */                  \
    __builtin_amdgcn_s_barrier();                                            \
  }

  // Prologue: stage slices 0,1 (slots 0..3); ensure slice 0 landed.
  STG_A(0, 0);
  STG_B(0, 1);
  STG_A(32, 2);
  STG_B(32, 3);
  VMCNT(4);  // retire {A,B}(0); {A,B}(1) stays in flight
  __builtin_amdgcn_s_barrier();

  // Slices 0..27 (each stages slice s+2; vmcnt(4) retires slice s+1).
  for (int g = 0; g < 7; ++g) {
    SLICE(0, 0, 1, 1, 4);
    SLICE(1, 32, 1, 1, 4);
    SLICE(2, 64, 1, 1, 4);
    SLICE(3, 96, 1, 1, 4);
    aS0 += 128;
    aS1 += 128;
    bS0 += 128;
    bS1 += 128;
  }
  // Tail: s=28 (stage 30), s=29 (stage 31), s=30 (vmcnt 0 retires 31), s=31.
  SLICE(0, 0, 1, 1, 4);
  SLICE(1, 32, 1, 1, 4);
  SLICE(2, 64, 0, 1, 0);
  SLICE(3, 96, 0, 0, 0);

  // Epilogue. C/D layout: col = lane&15, row = (lane>>4)*4 + reg (m89).
  const int col0 = n_tile * 256 + wn * 64 + (lane & 15);
  const int row0 = m_tile * 256 + wm * 128 + ((lane >> 4) << 2);
#pragma unroll
  for (int j = 0; j < 4; ++j) {
    float bv = bias[col0 + j * 16];
#pragma unroll
    for (int m = 0; m < 8; ++m) {
#pragma unroll
      for (int r = 0; r < 4; ++r) {
        C[(size_t)(row0 + m * 16 + r) * N_DIM + col0 + j * 16] =
            acc[m][j][r] + bv;
      }
    }
  }
#undef STG_A
#undef STG_B
#undef SLICE
}

extern "C" void kernel_launch(void* const* d_in, const int* in_sizes, int n_in,
                              void* d_out, int out_size, void* d_ws,
                              size_t ws_size, hipStream_t stream) {
  const float* x = (const float*)d_in[0];     // 8*8192*1024 fp32
  const float* w = (const float*)d_in[1];     // 1024*1024 fp32
  const float* bias = (const float*)d_in[2];  // 1024 fp32
  float* out = (float*)d_out;                 // 65536*1024 fp32

  bf16_t* xd = (bf16_t*)d_ws;               // 128 MB
  bf16_t* wd = xd + (size_t)M_DIM * K_DIM;  // +2 MB

  quant_dequant_kernel<<<4608, 256, 0, stream>>>(
      x, xd, (long long)M_DIM * K_DIM / 8, w, wd,
      (long long)K_DIM * N_DIM / 8);

  mx_gemm<<<(M_DIM / 256) * (N_DIM / 256), 512, 0, stream>>>(xd, wd, bias,
                                                             out);
}

// Round 10
// 269.138 us; speedup vs baseline: 1.2576x; 1.0226x over previous
//
#include <hip/hip_runtime.h>
#include <stdint.h>

#define K_DIM 1024
#define N_DIM 1024
#define M_DIM 65536

typedef __bf16 bf16_t;
typedef __bf16 bf16x8 __attribute__((ext_vector_type(8)));
typedef float f32x4 __attribute__((ext_vector_type(4)));

#define GLOAD_LDS16(g, l) __builtin_amdgcn_global_load_lds( \
    (const __attribute__((address_space(1))) void*)(g),     \
    (__attribute__((address_space(3))) void*)(l), 16, 0, 0)

#define VMCNT(n) asm volatile("s_waitcnt vmcnt(%0)" ::"n"(n) : "memory")
#define LGKM(n) asm volatile("s_waitcnt lgkmcnt(%0)" ::"n"(n) : "memory")
#define SCHEDB() __builtin_amdgcn_sched_barrier(0)

// ---------------------------------------------------------------------------
// Quantize-dequantize to bf16.
// CORRECTNESS INVARIANT (r9 post-mortem): the 32-elem MX block is reduced by
// 4 ADJACENT LANES via shfl_xor(1/2), so lane L must always process item
// (base + L) with base a multiple of the wave width — i.e. consecutive lanes
// hold consecutive items. r9 broke this with per-thread item pairs (2i,2i+1).
// r10: MLP comes from unrolling the grid-stride loop by 2 — items i and
// i+stride (both sets lane-aligned), with both 32B loads issued before
// either compute. Arithmetic unchanged (fp32 div, floor, tie -> lower).
// ---------------------------------------------------------------------------
__device__ __forceinline__ void qd_compute(f32x4 v0, f32x4 v1,
                                           bf16_t* __restrict__ out,
                                           long long base) {
  float mx = 0.0f;
#pragma unroll
  for (int j = 0; j < 4; ++j) {
    mx = fmaxf(mx, fabsf(v0[j]));
    mx = fmaxf(mx, fabsf(v1[j]));
  }
  mx = fmaxf(mx, __shfl_xor(mx, 1));
  mx = fmaxf(mx, __shfl_xor(mx, 2));
  float s = fmaxf(mx / 7.5f, 1e-30f);
  bf16x8 o;
#pragma unroll
  for (int j = 0; j < 8; ++j) {
    float xv = (j < 4) ? v0[j] : v1[j - 4];
    float y = xv / s;  // fp32 div, like reference
    float m = fabsf(y);
    float h, hinv;
    if (m < 2.0f)      { h = 0.125f; hinv = 8.0f; }
    else if (m < 4.0f) { h = 0.25f;  hinv = 4.0f; }
    else               { h = 0.5f;   hinv = 2.0f; }
    float nn = m * hinv;  // exact (power-of-2 scale)
    float kf = floorf(nn);
    float fr = nn - kf;   // exact
    float up = (fr > 0.5f || (fr == 0.5f && y < 0.0f)) ? 1.0f : 0.0f;
    float q = fminf((kf + up) * h, 7.5f);
    o[j] = (bf16_t)(copysignf(q, y) * s);
  }
  *reinterpret_cast<bf16x8*>(out + base) = o;
}

__global__ __launch_bounds__(256) void quant_dequant_kernel(
    const float* __restrict__ x, bf16_t* __restrict__ xd, long long nx,
    const float* __restrict__ w, bf16_t* __restrict__ wd, long long nw) {
  if (blockIdx.x < 512) {
    // w: 131072 items, 512*256 threads -> exactly 1 item/thread (lane-aligned).
    long long i = (long long)blockIdx.x * blockDim.x + threadIdx.x;
    if (i < nw) {
      f32x4 v0 = *reinterpret_cast<const f32x4*>(w + i * 8);
      f32x4 v1 = *reinterpret_cast<const f32x4*>(w + i * 8 + 4);
      qd_compute(v0, v1, wd, i * 8);
    }
  } else {
    // x: grid-stride unrolled by 2; both items lane-aligned (i and i+tcnt
    // each have lane L at item base+L). nx = 8*tcnt exactly.
    long long tcnt = (long long)(gridDim.x - 512) * blockDim.x;
    long long i = (long long)(blockIdx.x - 512) * blockDim.x + threadIdx.x;
    for (; i < nx; i += 2 * tcnt) {
      long long i2 = i + tcnt;
      f32x4 a0 = *reinterpret_cast<const f32x4*>(x + i * 8);
      f32x4 a1 = *reinterpret_cast<const f32x4*>(x + i * 8 + 4);
      f32x4 b0 = *reinterpret_cast<const f32x4*>(x + i2 * 8);
      f32x4 b1 = *reinterpret_cast<const f32x4*>(x + i2 * 8 + 4);
      qd_compute(a0, a1, xd, i * 8);
      qd_compute(b0, b1, xd, i2 * 8);
    }
  }
}

// ---------------------------------------------------------------------------
// bf16 GEMM C = A*B^T + bias — r3 schedule, verbatim (best measured: 167 us,
// 823 TF ~ 97% of m248's 848 TF plain-HIP reference at this exact shape).
// 256x256 tile, BK=32, 8 waves (2M x 4N), 4-stage LDS ring (4 x 32KB),
// staging 3 K-tiles ahead, counted vmcnt (never 0 in the main loop):
//   A(t): read af1(t) | STAGE(t+3) | lgkm(4) | 16 MFMA (af0 x bf)
//   B(t): vmcnt(8) | lgkm(0) | s_barrier | pre-read bf,af0(t+1) |
//         16 MFMA (af1 x bf)
// Swizzle: phys 16B slot = logical ^ ((row>>1)&3) — 0 conflicts measured;
// staging source inverse-pre-swizzled (both-sides-or-neither rule).
// ---------------------------------------------------------------------------
__global__ __launch_bounds__(512, 2) void mx_gemm(
    const bf16_t* __restrict__ A, const bf16_t* __restrict__ B,
    const float* __restrict__ bias, float* __restrict__ C) {
  __shared__ char lds[131072];

  const int tid = threadIdx.x;
  const int lane = tid & 63;
  const int wid = tid >> 6;
  const int wm = wid >> 2;  // 0..1  (128-row half)
  const int wn = wid & 3;   // 0..3  (64-col slice)

  // XCD-grouped mapping (verified: A fetched ~once from HBM).
  const int b = blockIdx.x;
  const int xcd = b & 7;
  const int t = b >> 3;
  const int m_tile = xcd * 32 + (t >> 2);  // [0,256)
  const int n_tile = t & 3;                // [0,4)

  const int R0 = tid >> 2;
  const int c0 = ((tid & 3) ^ ((tid >> 3) & 3)) * 8;  // elems
  const bf16_t* aS0 = A + (size_t)(m_tile * 256 + R0) * K_DIM + c0;
  const bf16_t* aS1 = aS0 + (size_t)128 * K_DIM;
  const bf16_t* bS0 = B + (size_t)(n_tile * 256 + R0) * K_DIM + c0;
  const bf16_t* bS1 = bS0 + (size_t)128 * K_DIM;
  const int dstOff = tid * 16;

#define STAGE(u)                                         \
  {                                                      \
    char* sb_ = lds + ((u) & 3) * 32768;                 \
    const int ko_ = (u) * 32;                            \
    GLOAD_LDS16(aS0 + ko_, sb_ + dstOff);                \
    GLOAD_LDS16(aS1 + ko_, sb_ + 8192 + dstOff);         \
    GLOAD_LDS16(bS0 + ko_, sb_ + 16384 + dstOff);        \
    GLOAD_LDS16(bS1 + ko_, sb_ + 24576 + dstOff);        \
  }

  const int ps = (((lane >> 4) ^ ((lane >> 1) & 3)) << 4);
  const int rowb = (lane & 15) * 64 + ps;
  const int aOff = wm * 8192 + rowb;          // + half*4096 + i*1024
  const int bOff = 16384 + wn * 4096 + rowb;  // + j*1024

  f32x4 acc[8][4];
#pragma unroll
  for (int i = 0; i < 8; ++i)
#pragma unroll
    for (int j = 0; j < 4; ++j) acc[i][j] = (f32x4)(0.0f);

  bf16x8 bfA[4], bfB[4], afA[4], afB[4], af1[4];

#define PH_A(T, BF, AF0, DO_STG)                                          \
  {                                                                       \
    const char* sb_ = lds + ((T) & 3) * 32768;                            \
    _Pragma("unroll") for (int i = 0; i < 4; ++i) af1[i] =                \
        *reinterpret_cast<const bf16x8*>(sb_ + aOff + 4096 + i * 1024);   \
    if (DO_STG) STAGE((T) + 3);                                           \
    LGKM(4);                                                              \
    SCHEDB();                                                             \
    __builtin_amdgcn_s_setprio(1);                                        \
    _Pragma("unroll") for (int i = 0; i < 4; ++i)                         \
        _Pragma("unroll") for (int j = 0; j < 4; ++j) acc[i][j] =         \
            __builtin_amdgcn_mfma_f32_16x16x32_bf16(AF0[i], BF[j],        \
                                                    acc[i][j], 0, 0, 0);  \
    __builtin_amdgcn_s_setprio(0);                                        \
  }

#define PH_B(T, BF, NBF, NAF0, VMN, DO_PRE)                                  \
  {                                                                          \
    VMCNT(VMN);                                                              \
    LGKM(0);                                                                 \
    __builtin_amdgcn_s_barrier();                                            \
    SCHEDB();                                                                \
    if (DO_PRE) {                                                            \
      const char* sn_ = lds + (((T) + 1) & 3) * 32768;                       \
      _Pragma("unroll") for (int j = 0; j < 4; ++j) NBF[j] =                 \
          *reinterpret_cast<const bf16x8*>(sn_ + bOff + j * 1024);           \
      _Pragma("unroll") for (int i = 0; i < 4; ++i) NAF0[i] =                \
          *reinterpret_cast<const bf16x8*>(sn_ + aOff + i * 1024);           \
    }                                                                        \
    __builtin_amdgcn_s_setprio(1);                                           \
    _Pragma("unroll") for (int i = 0; i < 4; ++i)                            \
        _Pragma("unroll") for (int j = 0; j < 4; ++j) acc[4 + i][j] =        \
            __builtin_amdgcn_mfma_f32_16x16x32_bf16(af1[i], BF[j],           \
                                                    acc[4 + i][j], 0, 0, 0); \
    __builtin_amdgcn_s_setprio(0);                                           \
  }

  // Prologue: 3 K-tiles staged; wait tile 0; pre-read its bf/af0.
  STAGE(0);
  STAGE(1);
  STAGE(2);
  VMCNT(8);
  __builtin_amdgcn_s_barrier();
  SCHEDB();
#pragma unroll
  for (int j = 0; j < 4; ++j)
    bfA[j] = *reinterpret_cast<const bf16x8*>(lds + bOff + j * 1024);
#pragma unroll
  for (int i = 0; i < 4; ++i)
    afA[i] = *reinterpret_cast<const bf16x8*>(lds + aOff + i * 1024);

  for (int p = 0; p < 14; ++p) {
    const int u = 2 * p;
    PH_A(u, bfA, afA, true);
    PH_B(u, bfA, bfB, afB, 8, true);
    PH_A(u + 1, bfB, afB, true);
    PH_B(u + 1, bfB, bfA, afA, 8, true);
  }
  // t=28 (stages tile 31, the last)
  PH_A(28, bfA, afA, true);
  PH_B(28, bfA, bfB, afB, 8, true);
  // t=29: outstanding = tiles 30,31 (8 loads) -> wait 30's: vmcnt(4)
  PH_A(29, bfB, afB, false);
  PH_B(29, bfB, bfA, afA, 4, true);
  // t=30: outstanding = tile 31 (4 loads) -> vmcnt(0)
  PH_A(30, bfA, afA, false);
  PH_B(30, bfA, bfB, afB, 0, true);
  // t=31: final tile, no pre-read / no vmcnt / no barrier
  PH_A(31, bfB, afB, false);
  LGKM(0);
  SCHEDB();
#pragma unroll
  for (int i = 0; i < 4; ++i)
#pragma unroll
    for (int j = 0; j < 4; ++j)
      acc[4 + i][j] = __builtin_amdgcn_mfma_f32_16x16x32_bf16(
          af1[i], bfB[j], acc[4 + i][j], 0, 0, 0);

  // Epilogue. C/D layout: col = lane&15, row = (lane>>4)*4 + reg (m89).
  const int col0 = n_tile * 256 + wn * 64 + (lane & 15);
  const int row0 = m_tile * 256 + wm * 128 + ((lane >> 4) << 2);
#pragma unroll
  for (int j = 0; j < 4; ++j) {
    float bv = bias[col0 + j * 16];
#pragma unroll
    for (int m = 0; m < 8; ++m) {
#pragma unroll
      for (int r = 0; r < 4; ++r) {
        C[(size_t)(row0 + m * 16 + r) * N_DIM + col0 + j * 16] =
            acc[m][j][r] + bv;
      }
    }
  }
#undef STAGE
#undef PH_A
#undef PH_B
}

extern "C" void kernel_launch(void* const* d_in, const int* in_sizes, int n_in,
                              void* d_out, int out_size, void* d_ws,
                              size_t ws_size, hipStream_t stream) {
  const float* x = (const float*)d_in[0];     // 8*8192*1024 fp32
  const float* w = (const float*)d_in[1];     // 1024*1024 fp32
  const float* bias = (const float*)d_in[2];  // 1024 fp32
  float* out = (float*)d_out;                 // 65536*1024 fp32

  bf16_t* xd = (bf16_t*)d_ws;               // 128 MB
  bf16_t* wd = xd + (size_t)M_DIM * K_DIM;  // +2 MB

  quant_dequant_kernel<<<4608, 256, 0, stream>>>(
      x, xd, (long long)M_DIM * K_DIM / 8, w, wd,
      (long long)K_DIM * N_DIM / 8);

  mx_gemm<<<(M_DIM / 256) * (N_DIM / 256), 512, 0, stream>>>(xd, wd, bias,
                                                             out);
}